// Round 6
// baseline (514.086 us; speedup 1.0000x reference)
//
#include <hip/hip_runtime.h>
#include <hip/hip_bf16.h>
#include <math.h>

#define HH 226
#define WW 226
#define HWIMG (226*226)
#define PS 16
#define STP 14
#define TOK 256
#define NPATCH 512
#define NTOK (NPATCH*TOK)
#define OUT_ELEMS (2*64*226*226)

typedef unsigned int u32;
typedef unsigned short u16;
typedef __attribute__((ext_vector_type(8))) short short8;
typedef __attribute__((ext_vector_type(4))) float f32x4;

__device__ __forceinline__ float lo16(u32 u){ return __uint_as_float(u << 16); }
__device__ __forceinline__ float hi16(u32 u){ return __uint_as_float(u & 0xFFFF0000u); }
__device__ __forceinline__ u16 f2bf(float f){
    u32 u = __float_as_uint(f);
    u += 0x7FFFu + ((u >> 16) & 1u);
    return (u16)(u >> 16);
}
__device__ __forceinline__ u32 pack2(float a, float b){
#if defined(__gfx950__) && __has_builtin(__builtin_amdgcn_cvt_pk_bf16_f32)
    auto r = __builtin_amdgcn_cvt_pk_bf16_f32(a, b);   // v_cvt_pk_bf16_f32 (RNE)
    return *(u32*)&r;
#else
    return (u32)f2bf(a) | ((u32)f2bf(b) << 16);
#endif
}
__device__ __forceinline__ void unpack8(uint4 r, float* d){
    d[0]=lo16(r.x); d[1]=hi16(r.x); d[2]=lo16(r.y); d[3]=hi16(r.y);
    d[4]=lo16(r.z); d[5]=hi16(r.z); d[6]=lo16(r.w); d[7]=hi16(r.w);
}
__device__ __forceinline__ uint4 pack8(const float* a){
    uint4 uu;
    uu.x = pack2(a[0], a[1]);
    uu.y = pack2(a[2], a[3]);
    uu.z = pack2(a[4], a[5]);
    uu.w = pack2(a[6], a[7]);
    return uu;
}
__device__ __forceinline__ float gelu_f(float x){
    return 0.5f * x * (1.0f + erff(x * 0.70710678118654752f));
}

template<int N>
__device__ __forceinline__ void store_bf16(u32* dst, const float* a){
    uint4* p4 = (uint4*)(dst);
    #pragma unroll
    for (int w4 = 0; w4 < N/8; ++w4) p4[w4] = pack8(a + 8*w4);
}

// ---------------- K1: patch gather + LN1 (LDS) + QKV (scalar weights) ----------------
__global__ __launch_bounds__(512, 4) void k1_qkv(
    const float* __restrict__ x, const float* __restrict__ g1, const float* __restrict__ b1,
    const float* __restrict__ wq, const float* __restrict__ wk, const float* __restrict__ wv,
    float* __restrict__ t_out, u32* __restrict__ qo, u32* __restrict__ ko, u32* __restrict__ vo)
{
    __shared__ u32 ys[256*33];           // [tok][33] bf16-pairs, pad 33 -> conflict-free
    __shared__ float g_s[64], b_s[64];
    const int tid = threadIdx.x;
    if (tid < 64){ g_s[tid]=g1[tid]; b_s[tid]=b1[tid]; }

    const int p = blockIdx.x;
    const int bi = p >> 8, ph = (p >> 4) & 15, pw = p & 15;

    // ---- Phase A ----
    const int tok = tid >> 1, h = tid & 1;
    const int ti = tok >> 4, tj = tok & 15;
    const int r = ph*STP + ti, c = pw*STP + tj;
    const float* xb = x + ((size_t)bi*64 + 32*h)*HWIMG + (size_t)r*WW + c;
    const size_t gtokA = (size_t)p*TOK + tok;
    float* tp = t_out + gtokA*64 + 32*h;

    float v32[32];
    float s1 = 0.f, s2 = 0.f;
    #pragma unroll
    for (int c8 = 0; c8 < 4; ++c8){
        #pragma unroll
        for (int u = 0; u < 8; ++u){
            const float vv = xb[(size_t)(c8*8+u)*HWIMG];
            v32[c8*8+u] = vv;
            s1 += vv; s2 += vv*vv;
        }
        ((float4*)tp)[c8*2]   = make_float4(v32[c8*8+0],v32[c8*8+1],v32[c8*8+2],v32[c8*8+3]);
        ((float4*)tp)[c8*2+1] = make_float4(v32[c8*8+4],v32[c8*8+5],v32[c8*8+6],v32[c8*8+7]);
    }
    s1 += __shfl_xor(s1, 1);
    s2 += __shfl_xor(s2, 1);
    const float mu = s1 * (1.f/64.f);
    const float var = s2 * (1.f/64.f) - mu*mu;
    const float rs = rsqrtf(var + 1e-5f);
    __syncthreads();                      // g_s ready
    #pragma unroll
    for (int i2 = 0; i2 < 16; ++i2){
        const int kk = 32*h + 2*i2;
        const float a0 = (v32[2*i2]  -mu)*rs*g_s[kk]   + b_s[kk];
        const float a1 = (v32[2*i2+1]-mu)*rs*g_s[kk+1] + b_s[kk+1];
        ys[tok*33 + 16*h + i2] = pack2(a0, a1);
    }
    __syncthreads();                      // ys ready

    // ---- Phase B ----
    const int wid  = __builtin_amdgcn_readfirstlane(tid >> 6);  // 0..7, wave-uniform
    const int lane = tid & 63;
    const int tokB = ((wid & 3) << 6) + lane;
    const int og   = wid >> 2;            // 0/1: outputs 32*og .. 32*og+31
    const size_t gtokB = (size_t)p*TOK + tokB;
    const u32* yrow = ys + tokB*33;

    #pragma unroll
    for (int m = 0; m < 3; ++m){
        const float* wm = (m==0 ? wq : (m==1 ? wk : wv));
        u32* om = (m==0 ? qo : (m==1 ? ko : vo));
        #pragma unroll
        for (int q = 0; q < 2; ++q){
            const int ob = og*32 + q*16;  // wave-uniform output base
            float acc[16];
            #pragma unroll
            for (int o = 0; o < 16; ++o) acc[o] = 0.f;
            for (int c2 = 0; c2 < 32; ++c2){
                const u32 yw = yrow[c2];
                const float a0 = lo16(yw), a1 = hi16(yw);
                const float* w0 = wm + (2*c2)*64 + ob;   // uniform -> s_load
                const float* w1 = w0 + 64;
                #pragma unroll
                for (int o = 0; o < 16; ++o) acc[o] += a0*w0[o] + a1*w1[o];
            }
            uint4* dst = (uint4*)(om + gtokB*32 + og*16 + q*8);
            dst[0] = pack8(acc);
            dst[1] = pack8(acc+8);
        }
    }
}

// ---------------- K2: MFMA attention, block = (patch, q-half), wave = head ----------------
// Grid 1024 -> 4 blocks/CU (16 waves/CU) to hide the serial per-qt dep chain.
__global__ __launch_bounds__(256, 4) void k2_attn(
    const u16* __restrict__ qg, const u16* __restrict__ kg,
    const u16* __restrict__ vg, u16* __restrict__ og)   // og aliases qg
{
    __shared__ u16 plds[4][16*280];      // per-wave 16 rows x 280 u16 (560B stride)
    const int tid  = threadIdx.x;
    const int lane = tid & 63;
    const int h    = tid >> 6;           // wave = head
    const int p    = blockIdx.x >> 1;
    const int qh   = blockIdx.x & 1;     // q-half: tiles qh*8 .. qh*8+7
    const int c15  = lane & 15;
    const int quad = lane >> 4;
    const size_t pbase = (size_t)p * TOK * 64;   // u16 elements

    // V B-frags resident: vf[kb][j] = V[kb*32+quad*8+j][h*16+c15]
    short8 vf[8];
    #pragma unroll
    for (int kb = 0; kb < 8; ++kb){
        #pragma unroll
        for (int j = 0; j < 8; ++j)
            vf[kb][j] = (short)vg[pbase + (size_t)(kb*32 + quad*8 + j)*64 + h*16 + c15];
    }
    u16* pw = &plds[h][0];

    for (int qi = 0; qi < 8; ++qi){
        const int qt = qh*8 + qi;
        // Q A-frag (quads 2,3 are the K-pad -> zero)
        short8 af = {0,0,0,0,0,0,0,0};
        if (quad < 2)
            af = *(const short8*)(qg + pbase + (size_t)(qt*16 + c15)*64 + h*16 + quad*8);

        // QK^T: 16 k-tiles -> S strip (16 q x 256 k) in C layout
        f32x4 S[16];
        #pragma unroll
        for (int t = 0; t < 16; ++t){
            short8 bf = {0,0,0,0,0,0,0,0};
            if (quad < 2)
                bf = *(const short8*)(kg + pbase + (size_t)(t*16 + c15)*64 + h*16 + quad*8);
            f32x4 z = {0.f,0.f,0.f,0.f};
            S[t] = __builtin_amdgcn_mfma_f32_16x16x32_bf16(af, bf, z, 0, 0, 0);
        }

        // p = exp2(L * 0.25/ln2); row sums (rows quad*4+r over 16-lane col groups)
        float rsum[4] = {0.f,0.f,0.f,0.f};
        #pragma unroll
        for (int t = 0; t < 16; ++t){
            #pragma unroll
            for (int r = 0; r < 4; ++r){
                const float pe = exp2f(S[t][r] * 0.360673760222241f);
                S[t][r] = pe;
                rsum[r] += pe;
            }
        }
        #pragma unroll
        for (int r = 0; r < 4; ++r){
            rsum[r] += __shfl_xor(rsum[r], 1);
            rsum[r] += __shfl_xor(rsum[r], 2);
            rsum[r] += __shfl_xor(rsum[r], 4);
            rsum[r] += __shfl_xor(rsum[r], 8);
        }

        // P -> LDS (bf16, unnormalized), pair-packed b32 writes
        #pragma unroll
        for (int u = 0; u < 8; ++u){
            #pragma unroll
            for (int r = 0; r < 4; ++r){
                const float va = S[2*u][r],  vb = S[2*u+1][r];
                const float pva = __shfl_xor(va, 1);
                const float pvb = __shfl_xor(vb, 1);
                const int row = quad*4 + r;
                u32 wrd; int key;
                if ((lane & 1) == 0){ wrd = pack2(va, pva);  key = 2*u*16 + c15; }
                else                { wrd = pack2(pvb, vb);  key = (2*u+1)*16 + c15 - 1; }
                *(u32*)(pw + row*280 + key) = wrd;
            }
        }

        // PV: O[q][d], A = P from LDS, B = resident V frags; two chains for ILP
        f32x4 O0 = {0.f,0.f,0.f,0.f}, O1 = {0.f,0.f,0.f,0.f};
        #pragma unroll
        for (int kb = 0; kb < 4; ++kb){
            const short8 a0 = *(const short8*)(pw + c15*280 + (2*kb)*32 + quad*8);
            const short8 a1 = *(const short8*)(pw + c15*280 + (2*kb+1)*32 + quad*8);
            O0 = __builtin_amdgcn_mfma_f32_16x16x32_bf16(a0, vf[2*kb],   O0, 0, 0, 0);
            O1 = __builtin_amdgcn_mfma_f32_16x16x32_bf16(a1, vf[2*kb+1], O1, 0, 0, 0);
        }

        // normalize rows by softmax sum and store
        #pragma unroll
        for (int r = 0; r < 4; ++r){
            const float ov = (O0[r] + O1[r]) / rsum[r];
            og[pbase + (size_t)(qt*16 + quad*4 + r)*64 + h*16 + c15] = f2bf(ov);
        }
    }
}

// ---------------- K3: MFMA proj + residual + LN2 + fc1 + GELU ----------------
__global__ __launch_bounds__(256, 2) void k3_proj_fc1(
    const u16* __restrict__ og, float* __restrict__ t,
    const float* __restrict__ wp, const float* __restrict__ bp,
    const float* __restrict__ g2, const float* __restrict__ b2,
    const float* __restrict__ wf1, const float* __restrict__ bf1,
    u32* __restrict__ y3)
{
    __shared__ u16 strip[4][16*136];     // per-wave: 16 rows x 136 u16 (272B stride)
    __shared__ float bp_s[64], g_s[64], b_s[64], bf_s[128];
    const int tid  = threadIdx.x;
    const int lane = tid & 63;
    const int w    = tid >> 6;
    const int c15  = lane & 15;
    const int quad = lane >> 4;
    if (tid < 64){ bp_s[tid]=bp[tid]; g_s[tid]=g2[tid]; b_s[tid]=b2[tid]; }
    else if (tid >= 128){ const int j = tid - 128; bf_s[j] = bf1[j]; }
    __syncthreads();

    // resident B-frags (bf16): wp 2kb x 4nt, wf1 2kb x 8nt
    short8 wpf[2][4];
    short8 wff[2][8];
    #pragma unroll
    for (int kb = 0; kb < 2; ++kb){
        #pragma unroll
        for (int nt = 0; nt < 4; ++nt){
            #pragma unroll
            for (int j = 0; j < 8; ++j)
                wpf[kb][nt][j] = (short)f2bf(wp[(kb*32 + quad*8 + j)*64 + nt*16 + c15]);
        }
        #pragma unroll
        for (int nt = 0; nt < 8; ++nt){
            #pragma unroll
            for (int j = 0; j < 8; ++j)
                wff[kb][nt][j] = (short)f2bf(wf1[(kb*32 + quad*8 + j)*128 + nt*16 + c15]);
        }
    }

    const int p = blockIdx.x;
    const size_t pbase = (size_t)p * TOK;           // token index base
    u16* st = strip[w];
    u32* stw = (u32*)st;

    const float gch[4] = { g_s[0*16+c15], g_s[1*16+c15], g_s[2*16+c15], g_s[3*16+c15] };
    const float bch[4] = { b_s[0*16+c15], b_s[1*16+c15], b_s[2*16+c15], b_s[3*16+c15] };
    const float bpc[4] = { bp_s[0*16+c15], bp_s[1*16+c15], bp_s[2*16+c15], bp_s[3*16+c15] };

    for (int rt = 0; rt < 4; ++rt){
        const int T = w*64 + rt*16;                 // m-tile token base

        // proj A-frags
        short8 af[2];
        #pragma unroll
        for (int kb = 0; kb < 2; ++kb)
            af[kb] = *(const short8*)(og + (pbase + T + c15)*64 + kb*32 + quad*8);

        // proj MFMA (bias init)
        f32x4 C[4];
        #pragma unroll
        for (int nt = 0; nt < 4; ++nt){
            const float b = bpc[nt];
            C[nt] = (f32x4){b, b, b, b};
        }
        #pragma unroll
        for (int kb = 0; kb < 2; ++kb)
            #pragma unroll
            for (int nt = 0; nt < 4; ++nt)
                C[nt] = __builtin_amdgcn_mfma_f32_16x16x32_bf16(af[kb], wpf[kb][nt], C[nt], 0, 0, 0);

        // residual add + t2 store (64B segments)
        #pragma unroll
        for (int nt = 0; nt < 4; ++nt){
            #pragma unroll
            for (int r = 0; r < 4; ++r)
                C[nt][r] += t[(pbase + T + quad*4 + r)*64 + nt*16 + c15];
        }
        #pragma unroll
        for (int nt = 0; nt < 4; ++nt){
            #pragma unroll
            for (int r = 0; r < 4; ++r)
                t[(pbase + T + quad*4 + r)*64 + nt*16 + c15] = C[nt][r];
        }

        // LN2 row stats (row = quad*4 + r)
        float rs1[4] = {0,0,0,0}, rs2[4] = {0,0,0,0};
        #pragma unroll
        for (int nt = 0; nt < 4; ++nt)
            #pragma unroll
            for (int r = 0; r < 4; ++r){ rs1[r] += C[nt][r]; rs2[r] += C[nt][r]*C[nt][r]; }
        #pragma unroll
        for (int r = 0; r < 4; ++r){
            rs1[r] += __shfl_xor(rs1[r], 1); rs2[r] += __shfl_xor(rs2[r], 1);
            rs1[r] += __shfl_xor(rs1[r], 2); rs2[r] += __shfl_xor(rs2[r], 2);
            rs1[r] += __shfl_xor(rs1[r], 4); rs2[r] += __shfl_xor(rs2[r], 4);
            rs1[r] += __shfl_xor(rs1[r], 8); rs2[r] += __shfl_xor(rs2[r], 8);
        }
        float muv[4], rsg[4];
        #pragma unroll
        for (int r = 0; r < 4; ++r){
            muv[r] = rs1[r]*(1.f/64.f);
            const float var = rs2[r]*(1.f/64.f) - muv[r]*muv[r];
            rsg[r] = rsqrtf(var + 1e-5f);
        }

        // normalized y -> strip (bf16, pair-packed b32 writes)
        #pragma unroll
        for (int nt = 0; nt < 4; ++nt){
            float yv[4];
            #pragma unroll
            for (int r = 0; r < 4; ++r)
                yv[r] = (C[nt][r]-muv[r])*rsg[r]*gch[nt] + bch[nt];
            #pragma unroll
            for (int r2 = 0; r2 < 2; ++r2){
                const float pv0 = __shfl_xor(yv[2*r2],   1);
                const float pv1 = __shfl_xor(yv[2*r2+1], 1);
                u32 wrd; int row;
                if ((lane & 1) == 0){ wrd = pack2(yv[2*r2], pv0);  row = quad*4 + 2*r2; }
                else                { wrd = pack2(pv1, yv[2*r2+1]); row = quad*4 + 2*r2 + 1; }
                *(u32*)(st + row*136 + nt*16 + (c15 & ~1)) = wrd;
            }
        }

        // fc1 A-frags from strip
        short8 pa[2];
        #pragma unroll
        for (int kb = 0; kb < 2; ++kb)
            pa[kb] = *(const short8*)(st + c15*136 + kb*32 + quad*8);

        // fc1 MFMA (bias init)
        f32x4 F[8];
        #pragma unroll
        for (int nt = 0; nt < 8; ++nt){
            const float b = bf_s[nt*16 + c15];
            F[nt] = (f32x4){b, b, b, b};
        }
        #pragma unroll
        for (int kb = 0; kb < 2; ++kb)
            #pragma unroll
            for (int nt = 0; nt < 8; ++nt)
                F[nt] = __builtin_amdgcn_mfma_f32_16x16x32_bf16(pa[kb], wff[kb][nt], F[nt], 0, 0, 0);

        // GELU
        #pragma unroll
        for (int nt = 0; nt < 8; ++nt)
            #pragma unroll
            for (int r = 0; r < 4; ++r)
                F[nt][r] = gelu_f(F[nt][r]);

        // y3 tile -> strip (pair-packed bf16)
        #pragma unroll
        for (int nt = 0; nt < 8; ++nt){
            #pragma unroll
            for (int r2 = 0; r2 < 2; ++r2){
                const float pv0 = __shfl_xor(F[nt][2*r2],   1);
                const float pv1 = __shfl_xor(F[nt][2*r2+1], 1);
                u32 wrd; int row;
                if ((lane & 1) == 0){ wrd = pack2(F[nt][2*r2], pv0);  row = quad*4 + 2*r2; }
                else                { wrd = pack2(pv1, F[nt][2*r2+1]); row = quad*4 + 2*r2 + 1; }
                *(u32*)(st + row*136 + nt*16 + (c15 & ~1)) = wrd;
            }
        }
        // coalesced y3 store: inst i covers token T+i, 64 u32 = 256B contiguous
        #pragma unroll
        for (int i = 0; i < 16; ++i){
            const u32 wv = stw[i*68 + lane];
            y3[(pbase + T + i)*64 + lane] = wv;
        }
    }
}

// ---------------- K4a: depthwise 5x5 conv + GELU + add (in-place on y3) ----------------
__global__ __launch_bounds__(256, 2) void k4a_dwconv(
    u32* y3, const float* __restrict__ wdw, const float* __restrict__ bdw)
{
    __shared__ u32 ys[400*33];       // 20x20 zero halo, 64 ch (32 words) + 1 pad
    __shared__ float wdwT[25*64];
    __shared__ float bdw_s[64];
    const int tid = threadIdx.x;
    const int p = blockIdx.x;
    const int ti = tid >> 4, tj = tid & 15;
    const int stok = (ti+2)*20 + (tj+2);
    const size_t gtok = (size_t)p*TOK + tid;
    for (int i = tid; i < 13200; i += 256) ys[i] = 0u;
    for (int half = 0; half < 2; ++half){
        __syncthreads();   // protect zero-init / previous phase reads
        for (int i = tid; i < 1600; i += 256){
            int chh = i/25, tap = i%25;
            wdwT[tap*64+chh] = wdw[(half*64+chh)*25 + tap];
        }
        if (tid < 64) bdw_s[tid] = bdw[half*64+tid];
        {
            const uint4* gp = (const uint4*)(y3 + gtok*64 + half*32);
            #pragma unroll
            for (int w = 0; w < 8; ++w){
                uint4 rr = gp[w];
                ys[stok*33 + w*4+0]=rr.x; ys[stok*33 + w*4+1]=rr.y;
                ys[stok*33 + w*4+2]=rr.z; ys[stok*33 + w*4+3]=rr.w;
            }
        }
        __syncthreads();
        const int base = stok*33;
        for (int ch2 = 0; ch2 < 32; ++ch2){
            float a0 = bdw_s[2*ch2], a1 = bdw_s[2*ch2+1];
            #pragma unroll
            for (int tap = 0; tap < 25; ++tap){
                const int di = tap/5, dj = tap%5;
                const int woff = ((di-2)*20 + (dj-2))*33;
                const u32 w0 = ys[base + woff + ch2];
                a0 += lo16(w0)*wdwT[tap*64+2*ch2];
                a1 += hi16(w0)*wdwT[tap*64+2*ch2+1];
            }
            const u32 own = ys[base + ch2];
            const float o0 = lo16(own) + gelu_f(a0);
            const float o1 = hi16(own) + gelu_f(a1);
            y3[gtok*64 + half*32 + ch2] = pack2(o0, o1);
        }
    }
}

// ---------------- K4b: fc2 + residual -> t3 [patch][ch][tok] ----------------
__global__ __launch_bounds__(256, 4) void k4b_fc2(
    const u32* __restrict__ y3, const float* __restrict__ t2,
    const float* __restrict__ wf2, const float* __restrict__ bf2,
    float* __restrict__ t3)
{
    __shared__ float wf_s[8192];
    __shared__ float bf_s[64];
    const int tid = threadIdx.x;
    for (int i = tid; i < 8192; i += 256) wf_s[i] = wf2[i];
    if (tid < 64) bf_s[tid] = bf2[tid];
    __syncthreads();
    const int p = blockIdx.x;
    const size_t gtok = (size_t)p*TOK + tid;
    float acc[64];
    #pragma unroll
    for (int d = 0; d < 64; ++d) acc[d] = bf_s[d];
    const uint4* yp = (const uint4*)(y3 + gtok*64);
    for (int c8 = 0; c8 < 16; ++c8){
        float a8[8]; unpack8(yp[c8], a8);
        #pragma unroll
        for (int u = 0; u < 8; ++u){
            const float a = a8[u];
            const float* wr = wf_s + (c8*8+u)*64;
            #pragma unroll
            for (int d = 0; d < 64; ++d) acc[d] += a*wr[d];
        }
    }
    const float* tp = t2 + gtok*64;
    #pragma unroll
    for (int q4 = 0; q4 < 16; ++q4){
        float4 tv = ((const float4*)tp)[q4];
        acc[q4*4+0]+=tv.x; acc[q4*4+1]+=tv.y; acc[q4*4+2]+=tv.z; acc[q4*4+3]+=tv.w;
    }
    float* t3p = t3 + (size_t)p*16384 + tid;
    #pragma unroll
    for (int d = 0; d < 64; ++d) t3p[d*256] = acc[d];
}

// ---------------- K5: overlap-add gather + averaging ----------------
__global__ __launch_bounds__(256, 4) void k5_reverse(
    const float* __restrict__ t3, float* __restrict__ out)
{
    const int e = blockIdx.x*256 + threadIdx.x;
    if (e >= OUT_ELEMS) return;
    const int c = e % WW;
    int tmp = e / WW;
    const int r = tmp % HH;
    tmp /= HH;
    const int ch = tmp & 63;
    const int b = tmp >> 6;
    int pr = r/14; if (pr > 15) pr = 15;
    int pc = c/14; if (pc > 15) pc = 15;
    const int ra = r - pr*14, ca = c - pc*14;
    const int rb = ra + 14, cb = ca + 14;
    const bool hr = (pr >= 1) && (rb < 16);
    const bool hc = (pc >= 1) && (cb < 16);
    #define T3IDX(PH,PC,I,J) (((((b*16+(PH))*16+(PC))*64 + ch) << 8) + (I)*16 + (J))
    float s = t3[T3IDX(pr,pc,ra,ca)];
    if (hr)       s += t3[T3IDX(pr-1,pc,  rb,ca)];
    if (hc)       s += t3[T3IDX(pr,  pc-1,ra,cb)];
    if (hr && hc) s += t3[T3IDX(pr-1,pc-1,rb,cb)];
    const float f = (hr ? 0.5f : 1.f) * (hc ? 0.5f : 1.f);
    out[e] = s * f;
    #undef T3IDX
}

extern "C" void kernel_launch(void* const* d_in, const int* in_sizes, int n_in,
                              void* d_out, int out_size, void* d_ws, size_t ws_size,
                              hipStream_t stream)
{
    const float* x    = (const float*)d_in[0];
    const float* g1   = (const float*)d_in[1];
    const float* b1   = (const float*)d_in[2];
    const float* wq   = (const float*)d_in[3];
    const float* wk   = (const float*)d_in[4];
    const float* wv   = (const float*)d_in[5];
    const float* wp   = (const float*)d_in[6];
    const float* bp   = (const float*)d_in[7];
    const float* g2   = (const float*)d_in[8];
    const float* b2   = (const float*)d_in[9];
    const float* wf1  = (const float*)d_in[10];
    const float* bf1  = (const float*)d_in[11];
    const float* wdw  = (const float*)d_in[12];
    const float* bdw  = (const float*)d_in[13];
    const float* wf2  = (const float*)d_in[14];
    const float* bf2  = (const float*)d_in[15];

    char* ws = (char*)d_ws;
    // layout (bytes):
    //   [0,        33554432)  t   fp32  (becomes t2 in-place in k3)
    //   [33554432, 50331648)  q   bf16  (k2 output o overwrites it)
    //   [50331648, 67108864)  k   bf16  \  t3 fp32 aliases k+v after k2
    //   [67108864, 83886080)  v   bf16  /
    //   [83886080, 117440512) y3  bf16  (128/token; k4a updates in place)
    float* t  = (float*)(ws);
    u32* q    = (u32*)(ws + 33554432);
    u32* k    = (u32*)(ws + 50331648);
    u32* v    = (u32*)(ws + 67108864);
    float* t3 = (float*)(ws + 50331648);
    u32* y3   = (u32*)(ws + 83886080);
    float* out = (float*)d_out;

    k1_qkv     <<<NPATCH,   512, 0, stream>>>(x, g1, b1, wq, wk, wv, t, q, k, v);
    k2_attn    <<<NPATCH*2, 256, 0, stream>>>((const u16*)q, (const u16*)k, (const u16*)v, (u16*)q);
    k3_proj_fc1<<<NPATCH,   256, 0, stream>>>((const u16*)q, t, wp, bp, g2, b2, wf1, bf1, y3);
    k4a_dwconv <<<NPATCH,   256, 0, stream>>>(y3, wdw, bdw);
    k4b_fc2    <<<NPATCH,   256, 0, stream>>>(y3, t, wf2, bf2, t3);
    k5_reverse <<<25538,    256, 0, stream>>>(t3, out);
}

// Round 7
// 473.478 us; speedup vs baseline: 1.0858x; 1.0858x over previous
//
#include <hip/hip_runtime.h>
#include <hip/hip_bf16.h>
#include <math.h>

#define HH 226
#define WW 226
#define HWIMG (226*226)
#define PS 16
#define STP 14
#define TOK 256
#define NPATCH 512
#define NTOK (NPATCH*TOK)
#define OUT_ELEMS (2*64*226*226)

typedef unsigned int u32;
typedef unsigned short u16;
typedef __attribute__((ext_vector_type(8))) short short8;
typedef __attribute__((ext_vector_type(4))) float f32x4;

__device__ __forceinline__ float lo16(u32 u){ return __uint_as_float(u << 16); }
__device__ __forceinline__ float hi16(u32 u){ return __uint_as_float(u & 0xFFFF0000u); }
__device__ __forceinline__ u16 f2bf(float f){
    u32 u = __float_as_uint(f);
    u += 0x7FFFu + ((u >> 16) & 1u);
    return (u16)(u >> 16);
}
__device__ __forceinline__ u32 pack2(float a, float b){
#if defined(__gfx950__) && __has_builtin(__builtin_amdgcn_cvt_pk_bf16_f32)
    auto r = __builtin_amdgcn_cvt_pk_bf16_f32(a, b);   // v_cvt_pk_bf16_f32 (RNE)
    return *(u32*)&r;
#else
    return (u32)f2bf(a) | ((u32)f2bf(b) << 16);
#endif
}
__device__ __forceinline__ void unpack8(uint4 r, float* d){
    d[0]=lo16(r.x); d[1]=hi16(r.x); d[2]=lo16(r.y); d[3]=hi16(r.y);
    d[4]=lo16(r.z); d[5]=hi16(r.z); d[6]=lo16(r.w); d[7]=hi16(r.w);
}
__device__ __forceinline__ uint4 pack8(const float* a){
    uint4 uu;
    uu.x = pack2(a[0], a[1]);
    uu.y = pack2(a[2], a[3]);
    uu.z = pack2(a[4], a[5]);
    uu.w = pack2(a[6], a[7]);
    return uu;
}
__device__ __forceinline__ float gelu_f(float x){
    return 0.5f * x * (1.0f + erff(x * 0.70710678118654752f));
}

template<int N>
__device__ __forceinline__ void store_bf16(u32* dst, const float* a){
    uint4* p4 = (uint4*)(dst);
    #pragma unroll
    for (int w4 = 0; w4 < N/8; ++w4) p4[w4] = pack8(a + 8*w4);
}

// ---------------- K1: patch gather + LN1 (LDS) + QKV (scalar weights) ----------------
__global__ __launch_bounds__(512, 4) void k1_qkv(
    const float* __restrict__ x, const float* __restrict__ g1, const float* __restrict__ b1,
    const float* __restrict__ wq, const float* __restrict__ wk, const float* __restrict__ wv,
    float* __restrict__ t_out, u32* __restrict__ qo, u32* __restrict__ ko, u32* __restrict__ vo)
{
    __shared__ u32 ys[256*33];           // [tok][33] bf16-pairs, pad 33 -> conflict-free
    __shared__ float g_s[64], b_s[64];
    const int tid = threadIdx.x;
    if (tid < 64){ g_s[tid]=g1[tid]; b_s[tid]=b1[tid]; }

    const int p = blockIdx.x;
    const int bi = p >> 8, ph = (p >> 4) & 15, pw = p & 15;

    // ---- Phase A ----
    const int tok = tid >> 1, h = tid & 1;
    const int ti = tok >> 4, tj = tok & 15;
    const int r = ph*STP + ti, c = pw*STP + tj;
    const float* xb = x + ((size_t)bi*64 + 32*h)*HWIMG + (size_t)r*WW + c;
    const size_t gtokA = (size_t)p*TOK + tok;
    float* tp = t_out + gtokA*64 + 32*h;

    float v32[32];
    float s1 = 0.f, s2 = 0.f;
    #pragma unroll
    for (int c8 = 0; c8 < 4; ++c8){
        #pragma unroll
        for (int u = 0; u < 8; ++u){
            const float vv = xb[(size_t)(c8*8+u)*HWIMG];
            v32[c8*8+u] = vv;
            s1 += vv; s2 += vv*vv;
        }
        ((float4*)tp)[c8*2]   = make_float4(v32[c8*8+0],v32[c8*8+1],v32[c8*8+2],v32[c8*8+3]);
        ((float4*)tp)[c8*2+1] = make_float4(v32[c8*8+4],v32[c8*8+5],v32[c8*8+6],v32[c8*8+7]);
    }
    s1 += __shfl_xor(s1, 1);
    s2 += __shfl_xor(s2, 1);
    const float mu = s1 * (1.f/64.f);
    const float var = s2 * (1.f/64.f) - mu*mu;
    const float rs = rsqrtf(var + 1e-5f);
    __syncthreads();                      // g_s ready
    #pragma unroll
    for (int i2 = 0; i2 < 16; ++i2){
        const int kk = 32*h + 2*i2;
        const float a0 = (v32[2*i2]  -mu)*rs*g_s[kk]   + b_s[kk];
        const float a1 = (v32[2*i2+1]-mu)*rs*g_s[kk+1] + b_s[kk+1];
        ys[tok*33 + 16*h + i2] = pack2(a0, a1);
    }
    __syncthreads();                      // ys ready

    // ---- Phase B ----
    const int wid  = __builtin_amdgcn_readfirstlane(tid >> 6);  // 0..7, wave-uniform
    const int lane = tid & 63;
    const int tokB = ((wid & 3) << 6) + lane;
    const int og   = wid >> 2;            // 0/1: outputs 32*og .. 32*og+31
    const size_t gtokB = (size_t)p*TOK + tokB;
    const u32* yrow = ys + tokB*33;

    #pragma unroll
    for (int m = 0; m < 3; ++m){
        const float* wm = (m==0 ? wq : (m==1 ? wk : wv));
        u32* om = (m==0 ? qo : (m==1 ? ko : vo));
        #pragma unroll
        for (int q = 0; q < 2; ++q){
            const int ob = og*32 + q*16;  // wave-uniform output base
            float acc[16];
            #pragma unroll
            for (int o = 0; o < 16; ++o) acc[o] = 0.f;
            for (int c2 = 0; c2 < 32; ++c2){
                const u32 yw = yrow[c2];
                const float a0 = lo16(yw), a1 = hi16(yw);
                const float* w0 = wm + (2*c2)*64 + ob;   // uniform -> s_load
                const float* w1 = w0 + 64;
                #pragma unroll
                for (int o = 0; o < 16; ++o) acc[o] += a0*w0[o] + a1*w1[o];
            }
            uint4* dst = (uint4*)(om + gtokB*32 + og*16 + q*8);
            dst[0] = pack8(acc);
            dst[1] = pack8(acc+8);
        }
    }
}

// ---------------- K2: MFMA attention, 1 block/patch, wave = head ----------------
// K and V frags RESIDENT in VGPRs (96 regs) -> each block reads Q/K/V exactly
// once from global; no per-qt K re-reads (round-6 L2-thrash fix).
__global__ __launch_bounds__(256, 2) void k2_attn(
    const u16* __restrict__ qg, const u16* __restrict__ kg,
    const u16* __restrict__ vg, u16* __restrict__ og)   // og aliases qg
{
    __shared__ u16 plds[4][16*280];      // per-wave 16 rows x 280 u16 (560B stride)
    const int tid  = threadIdx.x;
    const int lane = tid & 63;
    const int h    = tid >> 6;           // wave = head
    const int p    = blockIdx.x;
    const int c15  = lane & 15;
    const int quad = lane >> 4;
    const size_t pbase = (size_t)p * TOK * 64;   // u16 elements

    // K B-frags resident (16 tiles; quads 2,3 = K-dim zero pad)
    short8 kf[16];
    #pragma unroll
    for (int t = 0; t < 16; ++t){
        short8 bf = {0,0,0,0,0,0,0,0};
        if (quad < 2)
            bf = *(const short8*)(kg + pbase + (size_t)(t*16 + c15)*64 + h*16 + quad*8);
        kf[t] = bf;
    }
    // V B-frags resident: vf[kb][j] = V[kb*32+quad*8+j][h*16+c15]
    short8 vf[8];
    #pragma unroll
    for (int kb = 0; kb < 8; ++kb){
        #pragma unroll
        for (int j = 0; j < 8; ++j)
            vf[kb][j] = (short)vg[pbase + (size_t)(kb*32 + quad*8 + j)*64 + h*16 + c15];
    }
    u16* pw = &plds[h][0];

    for (int qt = 0; qt < 16; ++qt){
        // Q A-frag (quads 2,3 are the K-pad -> zero)
        short8 af = {0,0,0,0,0,0,0,0};
        if (quad < 2)
            af = *(const short8*)(qg + pbase + (size_t)(qt*16 + c15)*64 + h*16 + quad*8);

        // QK^T: 16 k-tiles -> S strip (16 q x 256 k) in C layout
        f32x4 S[16];
        #pragma unroll
        for (int t = 0; t < 16; ++t){
            f32x4 z = {0.f,0.f,0.f,0.f};
            S[t] = __builtin_amdgcn_mfma_f32_16x16x32_bf16(af, kf[t], z, 0, 0, 0);
        }

        // p = exp2(L * 0.25/ln2); row sums (rows quad*4+r over 16-lane col groups)
        float rsum[4] = {0.f,0.f,0.f,0.f};
        #pragma unroll
        for (int t = 0; t < 16; ++t){
            #pragma unroll
            for (int r = 0; r < 4; ++r){
                const float pe = exp2f(S[t][r] * 0.360673760222241f);
                S[t][r] = pe;
                rsum[r] += pe;
            }
        }
        #pragma unroll
        for (int r = 0; r < 4; ++r){
            rsum[r] += __shfl_xor(rsum[r], 1);
            rsum[r] += __shfl_xor(rsum[r], 2);
            rsum[r] += __shfl_xor(rsum[r], 4);
            rsum[r] += __shfl_xor(rsum[r], 8);
        }
        float rinv[4];
        #pragma unroll
        for (int r = 0; r < 4; ++r) rinv[r] = __builtin_amdgcn_rcpf(rsum[r]);

        // P -> LDS (bf16, unnormalized), pair-packed b32 writes
        #pragma unroll
        for (int u = 0; u < 8; ++u){
            #pragma unroll
            for (int r = 0; r < 4; ++r){
                const float va = S[2*u][r],  vb = S[2*u+1][r];
                const float pva = __shfl_xor(va, 1);
                const float pvb = __shfl_xor(vb, 1);
                const int row = quad*4 + r;
                u32 wrd; int key;
                if ((lane & 1) == 0){ wrd = pack2(va, pva);  key = 2*u*16 + c15; }
                else                { wrd = pack2(pvb, vb);  key = (2*u+1)*16 + c15 - 1; }
                *(u32*)(pw + row*280 + key) = wrd;
            }
        }

        // PV: O[q][d], A = P from LDS, B = resident V frags; two chains for ILP
        f32x4 O0 = {0.f,0.f,0.f,0.f}, O1 = {0.f,0.f,0.f,0.f};
        #pragma unroll
        for (int kb = 0; kb < 4; ++kb){
            const short8 a0 = *(const short8*)(pw + c15*280 + (2*kb)*32 + quad*8);
            const short8 a1 = *(const short8*)(pw + c15*280 + (2*kb+1)*32 + quad*8);
            O0 = __builtin_amdgcn_mfma_f32_16x16x32_bf16(a0, vf[2*kb],   O0, 0, 0, 0);
            O1 = __builtin_amdgcn_mfma_f32_16x16x32_bf16(a1, vf[2*kb+1], O1, 0, 0, 0);
        }

        // normalize rows by softmax sum (rcp) and store
        #pragma unroll
        for (int r = 0; r < 4; ++r){
            const float ov = (O0[r] + O1[r]) * rinv[r];
            og[pbase + (size_t)(qt*16 + quad*4 + r)*64 + h*16 + c15] = f2bf(ov);
        }
    }
}

// ---------------- K3: MFMA proj + residual + LN2 + fc1 + GELU ----------------
__global__ __launch_bounds__(256, 2) void k3_proj_fc1(
    const u16* __restrict__ og, float* __restrict__ t,
    const float* __restrict__ wp, const float* __restrict__ bp,
    const float* __restrict__ g2, const float* __restrict__ b2,
    const float* __restrict__ wf1, const float* __restrict__ bf1,
    u32* __restrict__ y3)
{
    __shared__ u16 strip[4][16*136];     // per-wave: 16 rows x 136 u16 (272B stride)
    __shared__ float bp_s[64], g_s[64], b_s[64], bf_s[128];
    const int tid  = threadIdx.x;
    const int lane = tid & 63;
    const int w    = tid >> 6;
    const int c15  = lane & 15;
    const int quad = lane >> 4;
    if (tid < 64){ bp_s[tid]=bp[tid]; g_s[tid]=g2[tid]; b_s[tid]=b2[tid]; }
    else if (tid >= 128){ const int j = tid - 128; bf_s[j] = bf1[j]; }
    __syncthreads();

    // resident B-frags (bf16): wp 2kb x 4nt, wf1 2kb x 8nt
    short8 wpf[2][4];
    short8 wff[2][8];
    #pragma unroll
    for (int kb = 0; kb < 2; ++kb){
        #pragma unroll
        for (int nt = 0; nt < 4; ++nt){
            #pragma unroll
            for (int j = 0; j < 8; ++j)
                wpf[kb][nt][j] = (short)f2bf(wp[(kb*32 + quad*8 + j)*64 + nt*16 + c15]);
        }
        #pragma unroll
        for (int nt = 0; nt < 8; ++nt){
            #pragma unroll
            for (int j = 0; j < 8; ++j)
                wff[kb][nt][j] = (short)f2bf(wf1[(kb*32 + quad*8 + j)*128 + nt*16 + c15]);
        }
    }

    const int p = blockIdx.x;
    const size_t pbase = (size_t)p * TOK;           // token index base
    u16* st = strip[w];
    u32* stw = (u32*)st;

    const float gch[4] = { g_s[0*16+c15], g_s[1*16+c15], g_s[2*16+c15], g_s[3*16+c15] };
    const float bch[4] = { b_s[0*16+c15], b_s[1*16+c15], b_s[2*16+c15], b_s[3*16+c15] };
    const float bpc[4] = { bp_s[0*16+c15], bp_s[1*16+c15], bp_s[2*16+c15], bp_s[3*16+c15] };

    for (int rt = 0; rt < 4; ++rt){
        const int T = w*64 + rt*16;                 // m-tile token base

        // proj A-frags
        short8 af[2];
        #pragma unroll
        for (int kb = 0; kb < 2; ++kb)
            af[kb] = *(const short8*)(og + (pbase + T + c15)*64 + kb*32 + quad*8);

        // proj MFMA (bias init)
        f32x4 C[4];
        #pragma unroll
        for (int nt = 0; nt < 4; ++nt){
            const float b = bpc[nt];
            C[nt] = (f32x4){b, b, b, b};
        }
        #pragma unroll
        for (int kb = 0; kb < 2; ++kb)
            #pragma unroll
            for (int nt = 0; nt < 4; ++nt)
                C[nt] = __builtin_amdgcn_mfma_f32_16x16x32_bf16(af[kb], wpf[kb][nt], C[nt], 0, 0, 0);

        // residual add + t2 store (64B segments)
        #pragma unroll
        for (int nt = 0; nt < 4; ++nt){
            #pragma unroll
            for (int r = 0; r < 4; ++r)
                C[nt][r] += t[(pbase + T + quad*4 + r)*64 + nt*16 + c15];
        }
        #pragma unroll
        for (int nt = 0; nt < 4; ++nt){
            #pragma unroll
            for (int r = 0; r < 4; ++r)
                t[(pbase + T + quad*4 + r)*64 + nt*16 + c15] = C[nt][r];
        }

        // LN2 row stats (row = quad*4 + r)
        float rs1[4] = {0,0,0,0}, rs2[4] = {0,0,0,0};
        #pragma unroll
        for (int nt = 0; nt < 4; ++nt)
            #pragma unroll
            for (int r = 0; r < 4; ++r){ rs1[r] += C[nt][r]; rs2[r] += C[nt][r]*C[nt][r]; }
        #pragma unroll
        for (int r = 0; r < 4; ++r){
            rs1[r] += __shfl_xor(rs1[r], 1); rs2[r] += __shfl_xor(rs2[r], 1);
            rs1[r] += __shfl_xor(rs1[r], 2); rs2[r] += __shfl_xor(rs2[r], 2);
            rs1[r] += __shfl_xor(rs1[r], 4); rs2[r] += __shfl_xor(rs2[r], 4);
            rs1[r] += __shfl_xor(rs1[r], 8); rs2[r] += __shfl_xor(rs2[r], 8);
        }
        float muv[4], rsg[4];
        #pragma unroll
        for (int r = 0; r < 4; ++r){
            muv[r] = rs1[r]*(1.f/64.f);
            const float var = rs2[r]*(1.f/64.f) - muv[r]*muv[r];
            rsg[r] = rsqrtf(var + 1e-5f);
        }

        // normalized y -> strip (bf16, pair-packed b32 writes)
        #pragma unroll
        for (int nt = 0; nt < 4; ++nt){
            float yv[4];
            #pragma unroll
            for (int r = 0; r < 4; ++r)
                yv[r] = (C[nt][r]-muv[r])*rsg[r]*gch[nt] + bch[nt];
            #pragma unroll
            for (int r2 = 0; r2 < 2; ++r2){
                const float pv0 = __shfl_xor(yv[2*r2],   1);
                const float pv1 = __shfl_xor(yv[2*r2+1], 1);
                u32 wrd; int row;
                if ((lane & 1) == 0){ wrd = pack2(yv[2*r2], pv0);  row = quad*4 + 2*r2; }
                else                { wrd = pack2(pv1, yv[2*r2+1]); row = quad*4 + 2*r2 + 1; }
                *(u32*)(st + row*136 + nt*16 + (c15 & ~1)) = wrd;
            }
        }

        // fc1 A-frags from strip
        short8 pa[2];
        #pragma unroll
        for (int kb = 0; kb < 2; ++kb)
            pa[kb] = *(const short8*)(st + c15*136 + kb*32 + quad*8);

        // fc1 MFMA (bias init)
        f32x4 F[8];
        #pragma unroll
        for (int nt = 0; nt < 8; ++nt){
            const float b = bf_s[nt*16 + c15];
            F[nt] = (f32x4){b, b, b, b};
        }
        #pragma unroll
        for (int kb = 0; kb < 2; ++kb)
            #pragma unroll
            for (int nt = 0; nt < 8; ++nt)
                F[nt] = __builtin_amdgcn_mfma_f32_16x16x32_bf16(pa[kb], wff[kb][nt], F[nt], 0, 0, 0);

        // GELU
        #pragma unroll
        for (int nt = 0; nt < 8; ++nt)
            #pragma unroll
            for (int r = 0; r < 4; ++r)
                F[nt][r] = gelu_f(F[nt][r]);

        // y3 tile -> strip (pair-packed bf16)
        #pragma unroll
        for (int nt = 0; nt < 8; ++nt){
            #pragma unroll
            for (int r2 = 0; r2 < 2; ++r2){
                const float pv0 = __shfl_xor(F[nt][2*r2],   1);
                const float pv1 = __shfl_xor(F[nt][2*r2+1], 1);
                u32 wrd; int row;
                if ((lane & 1) == 0){ wrd = pack2(F[nt][2*r2], pv0);  row = quad*4 + 2*r2; }
                else                { wrd = pack2(pv1, F[nt][2*r2+1]); row = quad*4 + 2*r2 + 1; }
                *(u32*)(st + row*136 + nt*16 + (c15 & ~1)) = wrd;
            }
        }
        // coalesced y3 store: inst i covers token T+i, 64 u32 = 256B contiguous
        #pragma unroll
        for (int i = 0; i < 16; ++i){
            const u32 wv = stw[i*68 + lane];
            y3[(pbase + T + i)*64 + lane] = wv;
        }
    }
}

// ---------------- K4a: depthwise 5x5 conv + GELU + add (in-place on y3) ----------------
__global__ __launch_bounds__(256, 2) void k4a_dwconv(
    u32* y3, const float* __restrict__ wdw, const float* __restrict__ bdw)
{
    __shared__ u32 ys[400*33];       // 20x20 zero halo, 64 ch (32 words) + 1 pad
    __shared__ float wdwT[25*64];
    __shared__ float bdw_s[64];
    const int tid = threadIdx.x;
    const int p = blockIdx.x;
    const int ti = tid >> 4, tj = tid & 15;
    const int stok = (ti+2)*20 + (tj+2);
    const size_t gtok = (size_t)p*TOK + tid;
    for (int i = tid; i < 13200; i += 256) ys[i] = 0u;
    for (int half = 0; half < 2; ++half){
        __syncthreads();   // protect zero-init / previous phase reads
        for (int i = tid; i < 1600; i += 256){
            int chh = i/25, tap = i%25;
            wdwT[tap*64+chh] = wdw[(half*64+chh)*25 + tap];
        }
        if (tid < 64) bdw_s[tid] = bdw[half*64+tid];
        {
            const uint4* gp = (const uint4*)(y3 + gtok*64 + half*32);
            #pragma unroll
            for (int w = 0; w < 8; ++w){
                uint4 rr = gp[w];
                ys[stok*33 + w*4+0]=rr.x; ys[stok*33 + w*4+1]=rr.y;
                ys[stok*33 + w*4+2]=rr.z; ys[stok*33 + w*4+3]=rr.w;
            }
        }
        __syncthreads();
        const int base = stok*33;
        for (int ch2 = 0; ch2 < 32; ++ch2){
            float a0 = bdw_s[2*ch2], a1 = bdw_s[2*ch2+1];
            #pragma unroll
            for (int tap = 0; tap < 25; ++tap){
                const int di = tap/5, dj = tap%5;
                const int woff = ((di-2)*20 + (dj-2))*33;
                const u32 w0 = ys[base + woff + ch2];
                a0 += lo16(w0)*wdwT[tap*64+2*ch2];
                a1 += hi16(w0)*wdwT[tap*64+2*ch2+1];
            }
            const u32 own = ys[base + ch2];
            const float o0 = lo16(own) + gelu_f(a0);
            const float o1 = hi16(own) + gelu_f(a1);
            y3[gtok*64 + half*32 + ch2] = pack2(o0, o1);
        }
    }
}

// ---------------- K4b: fc2 + residual -> t3 [patch][ch][tok] ----------------
__global__ __launch_bounds__(256, 4) void k4b_fc2(
    const u32* __restrict__ y3, const float* __restrict__ t2,
    const float* __restrict__ wf2, const float* __restrict__ bf2,
    float* __restrict__ t3)
{
    __shared__ float wf_s[8192];
    __shared__ float bf_s[64];
    const int tid = threadIdx.x;
    for (int i = tid; i < 8192; i += 256) wf_s[i] = wf2[i];
    if (tid < 64) bf_s[tid] = bf2[tid];
    __syncthreads();
    const int p = blockIdx.x;
    const size_t gtok = (size_t)p*TOK + tid;
    float acc[64];
    #pragma unroll
    for (int d = 0; d < 64; ++d) acc[d] = bf_s[d];
    const uint4* yp = (const uint4*)(y3 + gtok*64);
    for (int c8 = 0; c8 < 16; ++c8){
        float a8[8]; unpack8(yp[c8], a8);
        #pragma unroll
        for (int u = 0; u < 8; ++u){
            const float a = a8[u];
            const float* wr = wf_s + (c8*8+u)*64;
            #pragma unroll
            for (int d = 0; d < 64; ++d) acc[d] += a*wr[d];
        }
    }
    const float* tp = t2 + gtok*64;
    #pragma unroll
    for (int q4 = 0; q4 < 16; ++q4){
        float4 tv = ((const float4*)tp)[q4];
        acc[q4*4+0]+=tv.x; acc[q4*4+1]+=tv.y; acc[q4*4+2]+=tv.z; acc[q4*4+3]+=tv.w;
    }
    float* t3p = t3 + (size_t)p*16384 + tid;
    #pragma unroll
    for (int d = 0; d < 64; ++d) t3p[d*256] = acc[d];
}

// ---------------- K5: overlap-add gather + averaging ----------------
__global__ __launch_bounds__(256, 4) void k5_reverse(
    const float* __restrict__ t3, float* __restrict__ out)
{
    const int e = blockIdx.x*256 + threadIdx.x;
    if (e >= OUT_ELEMS) return;
    const int c = e % WW;
    int tmp = e / WW;
    const int r = tmp % HH;
    tmp /= HH;
    const int ch = tmp & 63;
    const int b = tmp >> 6;
    int pr = r/14; if (pr > 15) pr = 15;
    int pc = c/14; if (pc > 15) pc = 15;
    const int ra = r - pr*14, ca = c - pc*14;
    const int rb = ra + 14, cb = ca + 14;
    const bool hr = (pr >= 1) && (rb < 16);
    const bool hc = (pc >= 1) && (cb < 16);
    #define T3IDX(PH,PC,I,J) (((((b*16+(PH))*16+(PC))*64 + ch) << 8) + (I)*16 + (J))
    float s = t3[T3IDX(pr,pc,ra,ca)];
    if (hr)       s += t3[T3IDX(pr-1,pc,  rb,ca)];
    if (hc)       s += t3[T3IDX(pr,  pc-1,ra,cb)];
    if (hr && hc) s += t3[T3IDX(pr-1,pc-1,rb,cb)];
    const float f = (hr ? 0.5f : 1.f) * (hc ? 0.5f : 1.f);
    out[e] = s * f;
    #undef T3IDX
}

extern "C" void kernel_launch(void* const* d_in, const int* in_sizes, int n_in,
                              void* d_out, int out_size, void* d_ws, size_t ws_size,
                              hipStream_t stream)
{
    const float* x    = (const float*)d_in[0];
    const float* g1   = (const float*)d_in[1];
    const float* b1   = (const float*)d_in[2];
    const float* wq   = (const float*)d_in[3];
    const float* wk   = (const float*)d_in[4];
    const float* wv   = (const float*)d_in[5];
    const float* wp   = (const float*)d_in[6];
    const float* bp   = (const float*)d_in[7];
    const float* g2   = (const float*)d_in[8];
    const float* b2   = (const float*)d_in[9];
    const float* wf1  = (const float*)d_in[10];
    const float* bf1  = (const float*)d_in[11];
    const float* wdw  = (const float*)d_in[12];
    const float* bdw  = (const float*)d_in[13];
    const float* wf2  = (const float*)d_in[14];
    const float* bf2  = (const float*)d_in[15];

    char* ws = (char*)d_ws;
    // layout (bytes):
    //   [0,        33554432)  t   fp32  (becomes t2 in-place in k3)
    //   [33554432, 50331648)  q   bf16  (k2 output o overwrites it)
    //   [50331648, 67108864)  k   bf16  \  t3 fp32 aliases k+v after k2
    //   [67108864, 83886080)  v   bf16  /
    //   [83886080, 117440512) y3  bf16  (128/token; k4a updates in place)
    float* t  = (float*)(ws);
    u32* q    = (u32*)(ws + 33554432);
    u32* k    = (u32*)(ws + 50331648);
    u32* v    = (u32*)(ws + 67108864);
    float* t3 = (float*)(ws + 50331648);
    u32* y3   = (u32*)(ws + 83886080);
    float* out = (float*)d_out;

    k1_qkv     <<<NPATCH,   512, 0, stream>>>(x, g1, b1, wq, wk, wv, t, q, k, v);
    k2_attn    <<<NPATCH,   256, 0, stream>>>((const u16*)q, (const u16*)k, (const u16*)v, (u16*)q);
    k3_proj_fc1<<<NPATCH,   256, 0, stream>>>((const u16*)q, t, wp, bp, g2, b2, wf1, bf1, y3);
    k4a_dwconv <<<NPATCH,   256, 0, stream>>>(y3, wdw, bdw);
    k4b_fc2    <<<NPATCH,   256, 0, stream>>>(y3, t, wf2, bf2, t3);
    k5_reverse <<<25538,    256, 0, stream>>>(t3, out);
}

// Round 8
// 435.751 us; speedup vs baseline: 1.1798x; 1.0866x over previous
//
#include <hip/hip_runtime.h>
#include <hip/hip_bf16.h>
#include <math.h>

#define HH 226
#define WW 226
#define HWIMG (226*226)
#define PS 16
#define STP 14
#define TOK 256
#define NPATCH 512
#define NTOK (NPATCH*TOK)
#define OUT_ELEMS (2*64*226*226)

typedef unsigned int u32;
typedef unsigned short u16;
typedef __attribute__((ext_vector_type(8))) short short8;
typedef __attribute__((ext_vector_type(4))) float f32x4;

__device__ __forceinline__ float lo16(u32 u){ return __uint_as_float(u << 16); }
__device__ __forceinline__ float hi16(u32 u){ return __uint_as_float(u & 0xFFFF0000u); }
__device__ __forceinline__ u16 f2bf(float f){
    u32 u = __float_as_uint(f);
    u += 0x7FFFu + ((u >> 16) & 1u);
    return (u16)(u >> 16);
}
__device__ __forceinline__ u32 pack2(float a, float b){
#if defined(__gfx950__) && __has_builtin(__builtin_amdgcn_cvt_pk_bf16_f32)
    auto r = __builtin_amdgcn_cvt_pk_bf16_f32(a, b);   // v_cvt_pk_bf16_f32 (RNE)
    return *(u32*)&r;
#else
    return (u32)f2bf(a) | ((u32)f2bf(b) << 16);
#endif
}
__device__ __forceinline__ void unpack8(uint4 r, float* d){
    d[0]=lo16(r.x); d[1]=hi16(r.x); d[2]=lo16(r.y); d[3]=hi16(r.y);
    d[4]=lo16(r.z); d[5]=hi16(r.z); d[6]=lo16(r.w); d[7]=hi16(r.w);
}
__device__ __forceinline__ uint4 pack8(const float* a){
    uint4 uu;
    uu.x = pack2(a[0], a[1]);
    uu.y = pack2(a[2], a[3]);
    uu.z = pack2(a[4], a[5]);
    uu.w = pack2(a[6], a[7]);
    return uu;
}
__device__ __forceinline__ float gelu_f(float x){
    return 0.5f * x * (1.0f + erff(x * 0.70710678118654752f));
}

template<int N>
__device__ __forceinline__ void store_bf16(u32* dst, const float* a){
    uint4* p4 = (uint4*)(dst);
    #pragma unroll
    for (int w4 = 0; w4 < N/8; ++w4) p4[w4] = pack8(a + 8*w4);
}

// ---------------- K0: transpose wq/wk/wv -> bf16 [n][k] (B-frag friendly) ----------------
__global__ __launch_bounds__(256, 4) void k0_wt(
    const float* __restrict__ wq, const float* __restrict__ wk,
    const float* __restrict__ wv, u16* __restrict__ wt)
{
    const int i = blockIdx.x*256 + threadIdx.x;     // 48 blocks * 256 = 12288
    const int m = i >> 12, rem = i & 4095;
    const int kk = rem >> 6, n = rem & 63;          // consecutive tid -> consecutive n (coalesced read)
    const float* w = (m==0 ? wq : (m==1 ? wk : wv));
    wt[m*4096 + n*64 + kk] = f2bf(w[kk*64 + n]);
}

// ---------------- K1: patch gather + LN1 (LDS) + MFMA QKV ----------------
// Phase A: 2 threads/token gather x, LN1 via pair-shuffle, normalized bf16 -> ys
//          (row stride 72 u16 = 144 B, 16B-aligned for ds_read_b128).
// Phase B: 8 waves x 2 m-tiles; per matrix: B-frags = global b128 loads of the
//          k0-transposed weights (L1-hot), 8 MFMAs, pair-pack -> per-wave strip,
//          fully-coalesced 256B stores of q/k/v.
__global__ __launch_bounds__(512, 4) void k1_qkv(
    const float* __restrict__ x, const float* __restrict__ g1, const float* __restrict__ b1,
    const u16* __restrict__ wt,
    float* __restrict__ t_out, u32* __restrict__ qo, u32* __restrict__ ko, u32* __restrict__ vo)
{
    __shared__ u16 ys[256*72];           // [tok][72 u16]: 64 ch + 8 pad
    __shared__ u32 strip[8][16*34];      // per-wave 16 rows x (32 u32 + 2 pad)
    __shared__ float g_s[64], b_s[64];
    const int tid = threadIdx.x;
    if (tid < 64){ g_s[tid]=g1[tid]; b_s[tid]=b1[tid]; }

    const int p = blockIdx.x;
    const int bi = p >> 8, ph = (p >> 4) & 15, pw = p & 15;

    // ---- Phase A ----
    const int tok = tid >> 1, h = tid & 1;
    const int ti = tok >> 4, tj = tok & 15;
    const int r = ph*STP + ti, c = pw*STP + tj;
    const float* xb = x + ((size_t)bi*64 + 32*h)*HWIMG + (size_t)r*WW + c;
    const size_t gtokA = (size_t)p*TOK + tok;
    float* tp = t_out + gtokA*64 + 32*h;

    float v32[32];
    float s1 = 0.f, s2 = 0.f;
    #pragma unroll
    for (int c8 = 0; c8 < 4; ++c8){
        #pragma unroll
        for (int u = 0; u < 8; ++u){
            const float vv = xb[(size_t)(c8*8+u)*HWIMG];
            v32[c8*8+u] = vv;
            s1 += vv; s2 += vv*vv;
        }
        ((float4*)tp)[c8*2]   = make_float4(v32[c8*8+0],v32[c8*8+1],v32[c8*8+2],v32[c8*8+3]);
        ((float4*)tp)[c8*2+1] = make_float4(v32[c8*8+4],v32[c8*8+5],v32[c8*8+6],v32[c8*8+7]);
    }
    s1 += __shfl_xor(s1, 1);
    s2 += __shfl_xor(s2, 1);
    const float mu = s1 * (1.f/64.f);
    const float var = s2 * (1.f/64.f) - mu*mu;
    const float rs = rsqrtf(var + 1e-5f);
    __syncthreads();                      // g_s ready
    u32* ysw = (u32*)ys;
    #pragma unroll
    for (int i2 = 0; i2 < 16; ++i2){
        const int kk = 32*h + 2*i2;
        const float a0 = (v32[2*i2]  -mu)*rs*g_s[kk]   + b_s[kk];
        const float a1 = (v32[2*i2+1]-mu)*rs*g_s[kk+1] + b_s[kk+1];
        ysw[tok*36 + 16*h + i2] = pack2(a0, a1);
    }
    __syncthreads();                      // ys ready

    // ---- Phase B ----
    const int lane = tid & 63;
    const int w8   = tid >> 6;           // wave 0..7
    const int c15  = lane & 15;
    const int quad = lane >> 4;
    u32* stw = strip[w8];
    const size_t ptok = (size_t)p * TOK;

    for (int mt = 0; mt < 2; ++mt){
        const int T = w8*32 + mt*16;     // m-tile token base
        short8 af[2];
        #pragma unroll
        for (int kb = 0; kb < 2; ++kb)
            af[kb] = *(const short8*)(ys + (T + c15)*72 + kb*32 + quad*8);

        #pragma unroll
        for (int m = 0; m < 3; ++m){
            // B-frags for this matrix (b128 loads, L1/L2-hot)
            short8 bf[2][4];
            #pragma unroll
            for (int kb = 0; kb < 2; ++kb)
                #pragma unroll
                for (int nt = 0; nt < 4; ++nt)
                    bf[kb][nt] = *(const short8*)(wt + m*4096 + (nt*16 + c15)*64 + kb*32 + quad*8);

            f32x4 C[4];
            #pragma unroll
            for (int nt = 0; nt < 4; ++nt) C[nt] = (f32x4){0.f,0.f,0.f,0.f};
            #pragma unroll
            for (int kb = 0; kb < 2; ++kb)
                #pragma unroll
                for (int nt = 0; nt < 4; ++nt)
                    C[nt] = __builtin_amdgcn_mfma_f32_16x16x32_bf16(af[kb], bf[kb][nt], C[nt], 0, 0, 0);

            // pair-pack C tiles -> strip (b32 writes, <=2-way banks)
            #pragma unroll
            for (int nt = 0; nt < 4; ++nt){
                #pragma unroll
                for (int r2 = 0; r2 < 2; ++r2){
                    const float pv0 = __shfl_xor(C[nt][2*r2],   1);
                    const float pv1 = __shfl_xor(C[nt][2*r2+1], 1);
                    u32 wrd; int row;
                    if ((lane & 1) == 0){ wrd = pack2(C[nt][2*r2], pv0);  row = quad*4 + 2*r2; }
                    else                { wrd = pack2(pv1, C[nt][2*r2+1]); row = quad*4 + 2*r2 + 1; }
                    stw[row*34 + nt*8 + (c15 >> 1)] = wrd;
                }
            }

            // coalesced store: 8 insts x 64 lanes x 4B = 16 token rows
            u32* om = (m==0 ? qo : (m==1 ? ko : vo));
            #pragma unroll
            for (int i = 0; i < 8; ++i){
                const int flat = i*64 + lane;
                const u32 wv = stw[(flat >> 5)*34 + (flat & 31)];
                om[(ptok + T)*32 + flat] = wv;
            }
        }
    }
}

// ---------------- K2: MFMA attention, 1 block/patch, wave = head ----------------
// K and V frags RESIDENT in VGPRs -> each block reads Q/K/V exactly once.
__global__ __launch_bounds__(256, 2) void k2_attn(
    const u16* __restrict__ qg, const u16* __restrict__ kg,
    const u16* __restrict__ vg, u16* __restrict__ og)   // og aliases qg
{
    __shared__ u16 plds[4][16*280];      // per-wave 16 rows x 280 u16 (560B stride)
    const int tid  = threadIdx.x;
    const int lane = tid & 63;
    const int h    = tid >> 6;           // wave = head
    const int p    = blockIdx.x;
    const int c15  = lane & 15;
    const int quad = lane >> 4;
    const size_t pbase = (size_t)p * TOK * 64;   // u16 elements

    // K B-frags resident (16 tiles; quads 2,3 = K-dim zero pad)
    short8 kf[16];
    #pragma unroll
    for (int t = 0; t < 16; ++t){
        short8 bf = {0,0,0,0,0,0,0,0};
        if (quad < 2)
            bf = *(const short8*)(kg + pbase + (size_t)(t*16 + c15)*64 + h*16 + quad*8);
        kf[t] = bf;
    }
    // V B-frags resident: vf[kb][j] = V[kb*32+quad*8+j][h*16+c15]
    short8 vf[8];
    #pragma unroll
    for (int kb = 0; kb < 8; ++kb){
        #pragma unroll
        for (int j = 0; j < 8; ++j)
            vf[kb][j] = (short)vg[pbase + (size_t)(kb*32 + quad*8 + j)*64 + h*16 + c15];
    }
    u16* pw = &plds[h][0];

    for (int qt = 0; qt < 16; ++qt){
        // Q A-frag (quads 2,3 are the K-pad -> zero)
        short8 af = {0,0,0,0,0,0,0,0};
        if (quad < 2)
            af = *(const short8*)(qg + pbase + (size_t)(qt*16 + c15)*64 + h*16 + quad*8);

        // QK^T: 16 k-tiles -> S strip (16 q x 256 k) in C layout
        f32x4 S[16];
        #pragma unroll
        for (int t = 0; t < 16; ++t){
            f32x4 z = {0.f,0.f,0.f,0.f};
            S[t] = __builtin_amdgcn_mfma_f32_16x16x32_bf16(af, kf[t], z, 0, 0, 0);
        }

        // p = exp2(L * 0.25/ln2); row sums (rows quad*4+r over 16-lane col groups)
        float rsum[4] = {0.f,0.f,0.f,0.f};
        #pragma unroll
        for (int t = 0; t < 16; ++t){
            #pragma unroll
            for (int r = 0; r < 4; ++r){
                const float pe = exp2f(S[t][r] * 0.360673760222241f);
                S[t][r] = pe;
                rsum[r] += pe;
            }
        }
        #pragma unroll
        for (int r = 0; r < 4; ++r){
            rsum[r] += __shfl_xor(rsum[r], 1);
            rsum[r] += __shfl_xor(rsum[r], 2);
            rsum[r] += __shfl_xor(rsum[r], 4);
            rsum[r] += __shfl_xor(rsum[r], 8);
        }
        float rinv[4];
        #pragma unroll
        for (int r = 0; r < 4; ++r) rinv[r] = __builtin_amdgcn_rcpf(rsum[r]);

        // P -> LDS (bf16, unnormalized), pair-packed b32 writes
        #pragma unroll
        for (int u = 0; u < 8; ++u){
            #pragma unroll
            for (int r = 0; r < 4; ++r){
                const float va = S[2*u][r],  vb = S[2*u+1][r];
                const float pva = __shfl_xor(va, 1);
                const float pvb = __shfl_xor(vb, 1);
                const int row = quad*4 + r;
                u32 wrd; int key;
                if ((lane & 1) == 0){ wrd = pack2(va, pva);  key = 2*u*16 + c15; }
                else                { wrd = pack2(pvb, vb);  key = (2*u+1)*16 + c15 - 1; }
                *(u32*)(pw + row*280 + key) = wrd;
            }
        }

        // PV: O[q][d], A = P from LDS, B = resident V frags; two chains for ILP
        f32x4 O0 = {0.f,0.f,0.f,0.f}, O1 = {0.f,0.f,0.f,0.f};
        #pragma unroll
        for (int kb = 0; kb < 4; ++kb){
            const short8 a0 = *(const short8*)(pw + c15*280 + (2*kb)*32 + quad*8);
            const short8 a1 = *(const short8*)(pw + c15*280 + (2*kb+1)*32 + quad*8);
            O0 = __builtin_amdgcn_mfma_f32_16x16x32_bf16(a0, vf[2*kb],   O0, 0, 0, 0);
            O1 = __builtin_amdgcn_mfma_f32_16x16x32_bf16(a1, vf[2*kb+1], O1, 0, 0, 0);
        }

        // normalize rows by softmax sum (rcp) and store
        #pragma unroll
        for (int r = 0; r < 4; ++r){
            const float ov = (O0[r] + O1[r]) * rinv[r];
            og[pbase + (size_t)(qt*16 + quad*4 + r)*64 + h*16 + c15] = f2bf(ov);
        }
    }
}

// ---------------- K3: MFMA proj + residual + LN2 + fc1 + GELU ----------------
__global__ __launch_bounds__(256, 2) void k3_proj_fc1(
    const u16* __restrict__ og, float* __restrict__ t,
    const float* __restrict__ wp, const float* __restrict__ bp,
    const float* __restrict__ g2, const float* __restrict__ b2,
    const float* __restrict__ wf1, const float* __restrict__ bf1,
    u32* __restrict__ y3)
{
    __shared__ u16 strip[4][16*136];     // per-wave: 16 rows x 136 u16 (272B stride)
    __shared__ float bp_s[64], g_s[64], b_s[64], bf_s[128];
    const int tid  = threadIdx.x;
    const int lane = tid & 63;
    const int w    = tid >> 6;
    const int c15  = lane & 15;
    const int quad = lane >> 4;
    if (tid < 64){ bp_s[tid]=bp[tid]; g_s[tid]=g2[tid]; b_s[tid]=b2[tid]; }
    else if (tid >= 128){ const int j = tid - 128; bf_s[j] = bf1[j]; }
    __syncthreads();

    // resident B-frags (bf16): wp 2kb x 4nt, wf1 2kb x 8nt
    short8 wpf[2][4];
    short8 wff[2][8];
    #pragma unroll
    for (int kb = 0; kb < 2; ++kb){
        #pragma unroll
        for (int nt = 0; nt < 4; ++nt){
            #pragma unroll
            for (int j = 0; j < 8; ++j)
                wpf[kb][nt][j] = (short)f2bf(wp[(kb*32 + quad*8 + j)*64 + nt*16 + c15]);
        }
        #pragma unroll
        for (int nt = 0; nt < 8; ++nt){
            #pragma unroll
            for (int j = 0; j < 8; ++j)
                wff[kb][nt][j] = (short)f2bf(wf1[(kb*32 + quad*8 + j)*128 + nt*16 + c15]);
        }
    }

    const int p = blockIdx.x;
    const size_t pbase = (size_t)p * TOK;           // token index base
    u16* st = strip[w];
    u32* stw = (u32*)st;

    const float gch[4] = { g_s[0*16+c15], g_s[1*16+c15], g_s[2*16+c15], g_s[3*16+c15] };
    const float bch[4] = { b_s[0*16+c15], b_s[1*16+c15], b_s[2*16+c15], b_s[3*16+c15] };
    const float bpc[4] = { bp_s[0*16+c15], bp_s[1*16+c15], bp_s[2*16+c15], bp_s[3*16+c15] };

    for (int rt = 0; rt < 4; ++rt){
        const int T = w*64 + rt*16;                 // m-tile token base

        // proj A-frags
        short8 af[2];
        #pragma unroll
        for (int kb = 0; kb < 2; ++kb)
            af[kb] = *(const short8*)(og + (pbase + T + c15)*64 + kb*32 + quad*8);

        // proj MFMA (bias init)
        f32x4 C[4];
        #pragma unroll
        for (int nt = 0; nt < 4; ++nt){
            const float b = bpc[nt];
            C[nt] = (f32x4){b, b, b, b};
        }
        #pragma unroll
        for (int kb = 0; kb < 2; ++kb)
            #pragma unroll
            for (int nt = 0; nt < 4; ++nt)
                C[nt] = __builtin_amdgcn_mfma_f32_16x16x32_bf16(af[kb], wpf[kb][nt], C[nt], 0, 0, 0);

        // residual add + t2 store (64B segments)
        #pragma unroll
        for (int nt = 0; nt < 4; ++nt){
            #pragma unroll
            for (int r = 0; r < 4; ++r)
                C[nt][r] += t[(pbase + T + quad*4 + r)*64 + nt*16 + c15];
        }
        #pragma unroll
        for (int nt = 0; nt < 4; ++nt){
            #pragma unroll
            for (int r = 0; r < 4; ++r)
                t[(pbase + T + quad*4 + r)*64 + nt*16 + c15] = C[nt][r];
        }

        // LN2 row stats (row = quad*4 + r)
        float rs1[4] = {0,0,0,0}, rs2[4] = {0,0,0,0};
        #pragma unroll
        for (int nt = 0; nt < 4; ++nt)
            #pragma unroll
            for (int r = 0; r < 4; ++r){ rs1[r] += C[nt][r]; rs2[r] += C[nt][r]*C[nt][r]; }
        #pragma unroll
        for (int r = 0; r < 4; ++r){
            rs1[r] += __shfl_xor(rs1[r], 1); rs2[r] += __shfl_xor(rs2[r], 1);
            rs1[r] += __shfl_xor(rs1[r], 2); rs2[r] += __shfl_xor(rs2[r], 2);
            rs1[r] += __shfl_xor(rs1[r], 4); rs2[r] += __shfl_xor(rs2[r], 4);
            rs1[r] += __shfl_xor(rs1[r], 8); rs2[r] += __shfl_xor(rs2[r], 8);
        }
        float muv[4], rsg[4];
        #pragma unroll
        for (int r = 0; r < 4; ++r){
            muv[r] = rs1[r]*(1.f/64.f);
            const float var = rs2[r]*(1.f/64.f) - muv[r]*muv[r];
            rsg[r] = rsqrtf(var + 1e-5f);
        }

        // normalized y -> strip (bf16, pair-packed b32 writes)
        #pragma unroll
        for (int nt = 0; nt < 4; ++nt){
            float yv[4];
            #pragma unroll
            for (int r = 0; r < 4; ++r)
                yv[r] = (C[nt][r]-muv[r])*rsg[r]*gch[nt] + bch[nt];
            #pragma unroll
            for (int r2 = 0; r2 < 2; ++r2){
                const float pv0 = __shfl_xor(yv[2*r2],   1);
                const float pv1 = __shfl_xor(yv[2*r2+1], 1);
                u32 wrd; int row;
                if ((lane & 1) == 0){ wrd = pack2(yv[2*r2], pv0);  row = quad*4 + 2*r2; }
                else                { wrd = pack2(pv1, yv[2*r2+1]); row = quad*4 + 2*r2 + 1; }
                *(u32*)(st + row*136 + nt*16 + (c15 & ~1)) = wrd;
            }
        }

        // fc1 A-frags from strip
        short8 pa[2];
        #pragma unroll
        for (int kb = 0; kb < 2; ++kb)
            pa[kb] = *(const short8*)(st + c15*136 + kb*32 + quad*8);

        // fc1 MFMA (bias init)
        f32x4 F[8];
        #pragma unroll
        for (int nt = 0; nt < 8; ++nt){
            const float b = bf_s[nt*16 + c15];
            F[nt] = (f32x4){b, b, b, b};
        }
        #pragma unroll
        for (int kb = 0; kb < 2; ++kb)
            #pragma unroll
            for (int nt = 0; nt < 8; ++nt)
                F[nt] = __builtin_amdgcn_mfma_f32_16x16x32_bf16(pa[kb], wff[kb][nt], F[nt], 0, 0, 0);

        // GELU
        #pragma unroll
        for (int nt = 0; nt < 8; ++nt)
            #pragma unroll
            for (int r = 0; r < 4; ++r)
                F[nt][r] = gelu_f(F[nt][r]);

        // y3 tile -> strip (pair-packed bf16)
        #pragma unroll
        for (int nt = 0; nt < 8; ++nt){
            #pragma unroll
            for (int r2 = 0; r2 < 2; ++r2){
                const float pv0 = __shfl_xor(F[nt][2*r2],   1);
                const float pv1 = __shfl_xor(F[nt][2*r2+1], 1);
                u32 wrd; int row;
                if ((lane & 1) == 0){ wrd = pack2(F[nt][2*r2], pv0);  row = quad*4 + 2*r2; }
                else                { wrd = pack2(pv1, F[nt][2*r2+1]); row = quad*4 + 2*r2 + 1; }
                *(u32*)(st + row*136 + nt*16 + (c15 & ~1)) = wrd;
            }
        }
        // coalesced y3 store: inst i covers token T+i, 64 u32 = 256B contiguous
        #pragma unroll
        for (int i = 0; i < 16; ++i){
            const u32 wv = stw[i*68 + lane];
            y3[(pbase + T + i)*64 + lane] = wv;
        }
    }
}

// ---------------- K4a: depthwise 5x5 conv + GELU + add (in-place on y3) ----------------
__global__ __launch_bounds__(256, 2) void k4a_dwconv(
    u32* y3, const float* __restrict__ wdw, const float* __restrict__ bdw)
{
    __shared__ u32 ys[400*33];       // 20x20 zero halo, 64 ch (32 words) + 1 pad
    __shared__ float wdwT[25*64];
    __shared__ float bdw_s[64];
    const int tid = threadIdx.x;
    const int p = blockIdx.x;
    const int ti = tid >> 4, tj = tid & 15;
    const int stok = (ti+2)*20 + (tj+2);
    const size_t gtok = (size_t)p*TOK + tid;
    for (int i = tid; i < 13200; i += 256) ys[i] = 0u;
    for (int half = 0; half < 2; ++half){
        __syncthreads();   // protect zero-init / previous phase reads
        for (int i = tid; i < 1600; i += 256){
            int chh = i/25, tap = i%25;
            wdwT[tap*64+chh] = wdw[(half*64+chh)*25 + tap];
        }
        if (tid < 64) bdw_s[tid] = bdw[half*64+tid];
        {
            const uint4* gp = (const uint4*)(y3 + gtok*64 + half*32);
            #pragma unroll
            for (int w = 0; w < 8; ++w){
                uint4 rr = gp[w];
                ys[stok*33 + w*4+0]=rr.x; ys[stok*33 + w*4+1]=rr.y;
                ys[stok*33 + w*4+2]=rr.z; ys[stok*33 + w*4+3]=rr.w;
            }
        }
        __syncthreads();
        const int base = stok*33;
        for (int ch2 = 0; ch2 < 32; ++ch2){
            float a0 = bdw_s[2*ch2], a1 = bdw_s[2*ch2+1];
            #pragma unroll
            for (int tap = 0; tap < 25; ++tap){
                const int di = tap/5, dj = tap%5;
                const int woff = ((di-2)*20 + (dj-2))*33;
                const u32 w0 = ys[base + woff + ch2];
                a0 += lo16(w0)*wdwT[tap*64+2*ch2];
                a1 += hi16(w0)*wdwT[tap*64+2*ch2+1];
            }
            const u32 own = ys[base + ch2];
            const float o0 = lo16(own) + gelu_f(a0);
            const float o1 = hi16(own) + gelu_f(a1);
            y3[gtok*64 + half*32 + ch2] = pack2(o0, o1);
        }
    }
}

// ---------------- K4b: fc2 + residual -> t3 [patch][ch][tok] ----------------
__global__ __launch_bounds__(256, 4) void k4b_fc2(
    const u32* __restrict__ y3, const float* __restrict__ t2,
    const float* __restrict__ wf2, const float* __restrict__ bf2,
    float* __restrict__ t3)
{
    __shared__ float wf_s[8192];
    __shared__ float bf_s[64];
    const int tid = threadIdx.x;
    for (int i = tid; i < 8192; i += 256) wf_s[i] = wf2[i];
    if (tid < 64) bf_s[tid] = bf2[tid];
    __syncthreads();
    const int p = blockIdx.x;
    const size_t gtok = (size_t)p*TOK + tid;
    float acc[64];
    #pragma unroll
    for (int d = 0; d < 64; ++d) acc[d] = bf_s[d];
    const uint4* yp = (const uint4*)(y3 + gtok*64);
    for (int c8 = 0; c8 < 16; ++c8){
        float a8[8]; unpack8(yp[c8], a8);
        #pragma unroll
        for (int u = 0; u < 8; ++u){
            const float a = a8[u];
            const float* wr = wf_s + (c8*8+u)*64;
            #pragma unroll
            for (int d = 0; d < 64; ++d) acc[d] += a*wr[d];
        }
    }
    const float* tp = t2 + gtok*64;
    #pragma unroll
    for (int q4 = 0; q4 < 16; ++q4){
        float4 tv = ((const float4*)tp)[q4];
        acc[q4*4+0]+=tv.x; acc[q4*4+1]+=tv.y; acc[q4*4+2]+=tv.z; acc[q4*4+3]+=tv.w;
    }
    float* t3p = t3 + (size_t)p*16384 + tid;
    #pragma unroll
    for (int d = 0; d < 64; ++d) t3p[d*256] = acc[d];
}

// ---------------- K5: overlap-add gather + averaging ----------------
__global__ __launch_bounds__(256, 4) void k5_reverse(
    const float* __restrict__ t3, float* __restrict__ out)
{
    const int e = blockIdx.x*256 + threadIdx.x;
    if (e >= OUT_ELEMS) return;
    const int c = e % WW;
    int tmp = e / WW;
    const int r = tmp % HH;
    tmp /= HH;
    const int ch = tmp & 63;
    const int b = tmp >> 6;
    int pr = r/14; if (pr > 15) pr = 15;
    int pc = c/14; if (pc > 15) pc = 15;
    const int ra = r - pr*14, ca = c - pc*14;
    const int rb = ra + 14, cb = ca + 14;
    const bool hr = (pr >= 1) && (rb < 16);
    const bool hc = (pc >= 1) && (cb < 16);
    #define T3IDX(PH,PC,I,J) (((((b*16+(PH))*16+(PC))*64 + ch) << 8) + (I)*16 + (J))
    float s = t3[T3IDX(pr,pc,ra,ca)];
    if (hr)       s += t3[T3IDX(pr-1,pc,  rb,ca)];
    if (hc)       s += t3[T3IDX(pr,  pc-1,ra,cb)];
    if (hr && hc) s += t3[T3IDX(pr-1,pc-1,rb,cb)];
    const float f = (hr ? 0.5f : 1.f) * (hc ? 0.5f : 1.f);
    out[e] = s * f;
    #undef T3IDX
}

extern "C" void kernel_launch(void* const* d_in, const int* in_sizes, int n_in,
                              void* d_out, int out_size, void* d_ws, size_t ws_size,
                              hipStream_t stream)
{
    const float* x    = (const float*)d_in[0];
    const float* g1   = (const float*)d_in[1];
    const float* b1   = (const float*)d_in[2];
    const float* wq   = (const float*)d_in[3];
    const float* wk   = (const float*)d_in[4];
    const float* wv   = (const float*)d_in[5];
    const float* wp   = (const float*)d_in[6];
    const float* bp   = (const float*)d_in[7];
    const float* g2   = (const float*)d_in[8];
    const float* b2   = (const float*)d_in[9];
    const float* wf1  = (const float*)d_in[10];
    const float* bf1  = (const float*)d_in[11];
    const float* wdw  = (const float*)d_in[12];
    const float* bdw  = (const float*)d_in[13];
    const float* wf2  = (const float*)d_in[14];
    const float* bf2  = (const float*)d_in[15];

    char* ws = (char*)d_ws;
    // layout (bytes):
    //   [0,        33554432)  t   fp32  (becomes t2 in-place in k3)
    //   [33554432, 50331648)  q   bf16  (k2 output o overwrites it)
    //   [50331648, 67108864)  k   bf16  \  t3 fp32 aliases k+v after k2
    //   [67108864, 83886080)  v   bf16  /
    //   [83886080, 117440512) y3  bf16  (128/token; k4a updates in place)
    // wt (transposed bf16 qkv weights, 24 KB) lives at the head of d_out —
    // consumed by k1, fully overwritten by k5 at the end.
    float* t  = (float*)(ws);
    u32* q    = (u32*)(ws + 33554432);
    u32* k    = (u32*)(ws + 50331648);
    u32* v    = (u32*)(ws + 67108864);
    float* t3 = (float*)(ws + 50331648);
    u32* y3   = (u32*)(ws + 83886080);
    u16* wt   = (u16*)d_out;
    float* out = (float*)d_out;

    k0_wt      <<<48,       256, 0, stream>>>(wq, wk, wv, wt);
    k1_qkv     <<<NPATCH,   512, 0, stream>>>(x, g1, b1, wt, t, q, k, v);
    k2_attn    <<<NPATCH,   256, 0, stream>>>((const u16*)q, (const u16*)k, (const u16*)v, (u16*)q);
    k3_proj_fc1<<<NPATCH,   256, 0, stream>>>((const u16*)q, t, wp, bp, g2, b2, wf1, bf1, y3);
    k4a_dwconv <<<NPATCH,   256, 0, stream>>>(y3, wdw, bdw);
    k4b_fc2    <<<NPATCH,   256, 0, stream>>>(y3, t, wf2, bf2, t3);
    k5_reverse <<<25538,    256, 0, stream>>>(t3, out);
}